// Round 1
// baseline (287.569 us; speedup 1.0000x reference)
//
#include <hip/hip_runtime.h>

constexpr int D    = 128;
constexpr int K    = 512;
constexpr int OUTD = 256;
constexpr int BN   = 16;   // points per block
constexpr int BK   = 32;   // k-tile
constexpr int NT   = 256;  // threads per block

constexpr int XP = D + 4;     // 132, padded row stride
constexpr int CP = D + 4;     // 132
constexpr int WP = OUTD + 4;  // 260
constexpr int RP = 33;

__global__ __launch_bounds__(NT, 2)
void rbf_fused(const float* __restrict__ x,
               const float* __restrict__ cen,
               const float* __restrict__ ls,
               const float* __restrict__ w,
               float* __restrict__ out)
{
    __shared__ float Xs[BN * XP];
    __shared__ float Cs[BK * CP];
    __shared__ float Wl[BK * WP];
    __shared__ float Rb[BN * RP];
    __shared__ float es[K];
    __shared__ float rsum[BN];

    const int t  = threadIdx.x;
    const int nb = blockIdx.x * BN;

    // eps^2 = exp(2*log_shape) for all kernels (once)
    for (int i = t; i < K; i += NT) es[i] = expf(2.0f * ls[i]);
    if (t < BN) rsum[t] = 0.0f;

    // stage X tile (16 x 128), float4 coalesced
    const float4* x4 = reinterpret_cast<const float4*>(x);
    for (int f = t; f < BN * (D / 4); f += NT) {
        int n = f >> 5, q = f & 31;
        float4 v = x4[(size_t)(nb + n) * (D / 4) + q];
        *reinterpret_cast<float4*>(&Xs[n * XP + q * 4]) = v;
    }
    __syncthreads();

    const int n_d = t & 15;   // distance phase: point row
    const int k_d = t >> 4;   // distance phase: kk (0..15), also kk+16
    const int oc  = t & 31;   // acc phase: output col base
    const int g   = t >> 5;   // acc phase: row group (0..7), rows g and g+8

    float acc[2][8];
#pragma unroll
    for (int m = 0; m < 2; ++m)
#pragma unroll
        for (int j = 0; j < 8; ++j) acc[m][j] = 0.0f;
    float rp = 0.0f;  // partial row-sum (for row n_d)

    const float4* c4 = reinterpret_cast<const float4*>(cen);
    const float4* w4 = reinterpret_cast<const float4*>(w);

    for (int kt = 0; kt < K / BK; ++kt) {
        const int k0 = kt * BK;

        // stage centers tile (32 x 128)
#pragma unroll
        for (int i = 0; i < (BK * (D / 4)) / NT; ++i) {  // 4 float4 per thread
            int f = t + i * NT;
            int kk = f >> 5, q = f & 31;
            float4 v = c4[(size_t)(k0 + kk) * (D / 4) + q];
            *reinterpret_cast<float4*>(&Cs[kk * CP + q * 4]) = v;
        }
        // stage W tile as Wl[kk][o]  (transposed on the fly)
#pragma unroll
        for (int i = 0; i < (BK * OUTD / 4) / NT; ++i) {  // 8 float4 per thread
            int f = t + i * NT;
            int o = f >> 3, q = f & 7;
            float4 v = w4[(size_t)o * (K / 4) + (k0 / 4) + q];
            Wl[(q * 4 + 0) * WP + o] = v.x;
            Wl[(q * 4 + 1) * WP + o] = v.y;
            Wl[(q * 4 + 2) * WP + o] = v.z;
            Wl[(q * 4 + 3) * WP + o] = v.w;
        }
        __syncthreads();

        // distance + exp: each thread does rows n_d, cols k_d and k_d+16
#pragma unroll
        for (int h = 0; h < 2; ++h) {
            const int kk = k_d + 16 * h;
            const float4* xr = reinterpret_cast<const float4*>(&Xs[n_d * XP]);
            const float4* cr = reinterpret_cast<const float4*>(&Cs[kk * CP]);
            float r2 = 0.0f;
#pragma unroll
            for (int q = 0; q < D / 4; ++q) {
                float4 a = xr[q], b = cr[q];
                float d0 = a.x - b.x, d1 = a.y - b.y;
                float d2 = a.z - b.z, d3 = a.w - b.w;
                r2 = fmaf(d0, d0, r2);
                r2 = fmaf(d1, d1, r2);
                r2 = fmaf(d2, d2, r2);
                r2 = fmaf(d3, d3, r2);
            }
            float rb = expf(-es[k0 + kk] * r2);
            Rb[n_d * RP + kk] = rb;
            rp += rb;
        }
        __syncthreads();

        // accumulate unnormalized out: acc[n][o] += phi[n][k] * W[o][k]
#pragma unroll 4
        for (int kk = 0; kk < BK; ++kk) {
            float r0 = Rb[g * RP + kk];
            float r1 = Rb[(g + 8) * RP + kk];
            const float* wr = &Wl[kk * WP + oc];
#pragma unroll
            for (int j = 0; j < 8; ++j) {
                float wv = wr[32 * j];
                acc[0][j] = fmaf(r0, wv, acc[0][j]);
                acc[1][j] = fmaf(r1, wv, acc[1][j]);
            }
        }
        __syncthreads();
    }

    atomicAdd(&rsum[n_d], rp);
    __syncthreads();

    // epilogue: divide by (rowsum + eps), store
#pragma unroll
    for (int m = 0; m < 2; ++m) {
        int n = g + 8 * m;
        float denom = rsum[n] + 1e-9f;
#pragma unroll
        for (int j = 0; j < 8; ++j) {
            out[(size_t)(nb + n) * OUTD + oc + 32 * j] = acc[m][j] / denom;
        }
    }
}

extern "C" void kernel_launch(void* const* d_in, const int* in_sizes, int n_in,
                              void* d_out, int out_size, void* d_ws, size_t ws_size,
                              hipStream_t stream) {
    const float* x   = (const float*)d_in[0];  // (16,512,128) -> N x 128
    const float* cen = (const float*)d_in[1];  // 512 x 128
    const float* ls  = (const float*)d_in[2];  // 512
    const float* w   = (const float*)d_in[3];  // 256 x 512
    float* out = (float*)d_out;                // N x 256

    const int N = in_sizes[0] / D;             // 8192
    dim3 grid(N / BN), block(NT);
    hipLaunchKernelGGL(rbf_fused, grid, block, 0, stream, x, cen, ls, w, out);
}

// Round 2
// 45.721 us; speedup vs baseline: 6.2897x; 6.2897x over previous
//
#include <hip/hip_runtime.h>

typedef float  f32x4 __attribute__((ext_vector_type(4)));
typedef short  s16x8 __attribute__((ext_vector_type(8)));

constexpr int D  = 128;   // feature dim (GEMM1 K-dim)
constexpr int K  = 512;   // number of RBF kernels
constexpr int O  = 256;   // output dim
constexpr int BN = 32;    // rows (points) per block
constexpr int KT = 32;    // kernel-tile
constexpr int NT = 256;   // threads (4 waves)
constexpr int DP = D + 8;   // padded bf16 row stride for X/C tiles
constexpr int WP = KT + 8;  // padded bf16 row stride for Ws/Ps

__device__ __forceinline__ ushort f2bf(float f) {
    uint u = __builtin_bit_cast(uint, f);
    return (ushort)((u + 0x7FFFu + ((u >> 16) & 1u)) >> 16);
}
__device__ __forceinline__ float bf2f(ushort h) {
    uint u = ((uint)h) << 16;
    return __builtin_bit_cast(float, u);
}

__global__ __launch_bounds__(NT)
void rbf_mfma(const float* __restrict__ x, const float* __restrict__ cen,
              const float* __restrict__ ls, const float* __restrict__ w,
              float* __restrict__ out)
{
    __shared__ ushort Xhi[BN][DP], Xlo[BN][DP];
    __shared__ ushort Chi[KT][DP], Clo[KT][DP];
    __shared__ ushort Ws[O][WP];      // Ws[o][k_local] bf16
    __shared__ ushort Ps[BN][WP];     // phi tile bf16, [n][k_local]
    __shared__ float  es[K];
    __shared__ float  xs2[BN], cs2[KT];
    __shared__ float  Ls2[2][BN];     // per-k-half row sums

    const int t    = threadIdx.x;
    const int lane = t & 63;
    const int wv   = t >> 6;      // wave 0..3
    const int nh   = wv >> 1;     // GEMM1: n-half
    const int kh   = wv & 1;      // GEMM1: k-half
    const int l15  = lane & 15;
    const int l4   = lane >> 4;   // 0..3
    const int nb   = blockIdx.x * BN;

    // eps^2 = exp(2*log_shape)
    for (int i = t; i < K; i += NT) es[i] = __expf(2.0f * ls[i]);

    // ---- stage X (32 x 128 fp32 -> bf16 hi/lo) + ||x||^2 ----
    {
        const float4* x4 = reinterpret_cast<const float4*>(x + (size_t)nb * D);
#pragma unroll
        for (int i = 0; i < 4; ++i) {
            int f = t + i * NT;
            int row = f >> 5, q = f & 31;
            float4 v = x4[row * 32 + q];
            ushort4 h, lo;
            h.x = f2bf(v.x); lo.x = f2bf(v.x - bf2f(h.x));
            h.y = f2bf(v.y); lo.y = f2bf(v.y - bf2f(h.y));
            h.z = f2bf(v.z); lo.z = f2bf(v.z - bf2f(h.z));
            h.w = f2bf(v.w); lo.w = f2bf(v.w - bf2f(h.w));
            *(ushort4*)&Xhi[row][q * 4] = h;
            *(ushort4*)&Xlo[row][q * 4] = lo;
            float s = v.x*v.x + v.y*v.y + v.z*v.z + v.w*v.w;
            s += __shfl_xor(s, 1);  s += __shfl_xor(s, 2);
            s += __shfl_xor(s, 4);  s += __shfl_xor(s, 8);
            s += __shfl_xor(s, 16);
            if (q == 0) xs2[row] = s;
        }
    }

    f32x4 oacc[2][4];
#pragma unroll
    for (int a = 0; a < 2; ++a)
#pragma unroll
        for (int b = 0; b < 4; ++b) oacc[a][b] = (f32x4){0.f, 0.f, 0.f, 0.f};
    float Lp[4] = {0.f, 0.f, 0.f, 0.f};

    const float4* c4 = reinterpret_cast<const float4*>(cen);
    const float4* w4 = reinterpret_cast<const float4*>(w);

    for (int kt = 0; kt < K / KT; ++kt) {
        const int k0 = kt * KT;

        // ---- stage centers tile (32 x 128) hi/lo + ||c||^2 ----
#pragma unroll
        for (int i = 0; i < 4; ++i) {
            int f = t + i * NT;
            int row = f >> 5, q = f & 31;
            float4 v = c4[(size_t)(k0 + row) * 32 + q];
            ushort4 h, lo;
            h.x = f2bf(v.x); lo.x = f2bf(v.x - bf2f(h.x));
            h.y = f2bf(v.y); lo.y = f2bf(v.y - bf2f(h.y));
            h.z = f2bf(v.z); lo.z = f2bf(v.z - bf2f(h.z));
            h.w = f2bf(v.w); lo.w = f2bf(v.w - bf2f(h.w));
            *(ushort4*)&Chi[row][q * 4] = h;
            *(ushort4*)&Clo[row][q * 4] = lo;
            float s = v.x*v.x + v.y*v.y + v.z*v.z + v.w*v.w;
            s += __shfl_xor(s, 1);  s += __shfl_xor(s, 2);
            s += __shfl_xor(s, 4);  s += __shfl_xor(s, 8);
            s += __shfl_xor(s, 16);
            if (q == 0) cs2[row] = s;
        }
        // ---- stage W tile: Ws[o][k_local], 256 x 32, bf16 ----
#pragma unroll
        for (int i = 0; i < 8; ++i) {
            int f = t + i * NT;
            int o = f >> 3, q = f & 7;
            float4 v = w4[(size_t)o * (K / 4) + kt * 8 + q];
            ushort4 h;
            h.x = f2bf(v.x); h.y = f2bf(v.y);
            h.z = f2bf(v.z); h.w = f2bf(v.w);
            *(ushort4*)&Ws[o][q * 4] = h;
        }
        __syncthreads();

        // ---- GEMM1: G = X . C^T (split bf16: hh + hl + lh) ----
        f32x4 g = (f32x4){0.f, 0.f, 0.f, 0.f};
#pragma unroll
        for (int ds = 0; ds < 4; ++ds) {
            int dcol = ds * 32 + l4 * 8;
            s16x8 ah = *(const s16x8*)&Xhi[nh * 16 + l15][dcol];
            s16x8 al = *(const s16x8*)&Xlo[nh * 16 + l15][dcol];
            s16x8 bh = *(const s16x8*)&Chi[kh * 16 + l15][dcol];
            s16x8 bl = *(const s16x8*)&Clo[kh * 16 + l15][dcol];
            g = __builtin_amdgcn_mfma_f32_16x16x32_bf16(ah, bh, g, 0, 0, 0);
            g = __builtin_amdgcn_mfma_f32_16x16x32_bf16(ah, bl, g, 0, 0, 0);
            g = __builtin_amdgcn_mfma_f32_16x16x32_bf16(al, bh, g, 0, 0, 0);
        }

        // ---- phi = exp(-es * r^2), accumulate row-sum, write P tile ----
#pragma unroll
        for (int r = 0; r < 4; ++r) {
            int nloc = nh * 16 + l4 * 4 + r;
            int kloc = kh * 16 + l15;
            float r2  = xs2[nloc] + cs2[kloc] - 2.0f * g[r];
            float arg = es[k0 + kloc] * r2;
            float ph  = __expf(-arg);
            Lp[r] += ph;
            Ps[nloc][kloc] = f2bf(ph);
        }
        __syncthreads();

        // ---- GEMM2: out += phi . W^T (single bf16 pass) ----
#pragma unroll
        for (int nt = 0; nt < 2; ++nt) {
            s16x8 a = *(const s16x8*)&Ps[nt * 16 + l15][l4 * 8];
#pragma unroll
            for (int ot = 0; ot < 4; ++ot) {
                s16x8 b = *(const s16x8*)&Ws[wv * 64 + ot * 16 + l15][l4 * 8];
                oacc[nt][ot] = __builtin_amdgcn_mfma_f32_16x16x32_bf16(a, b, oacc[nt][ot], 0, 0, 0);
            }
        }
        __syncthreads();
    }

    // ---- row-sum reduce (deterministic, no atomics) ----
#pragma unroll
    for (int r = 0; r < 4; ++r) {
        float s = Lp[r];
        s += __shfl_xor(s, 1);  s += __shfl_xor(s, 2);
        s += __shfl_xor(s, 4);  s += __shfl_xor(s, 8);
        if (l15 == 0) Ls2[kh][nh * 16 + l4 * 4 + r] = s;
    }
    __syncthreads();

    // ---- epilogue: normalize + store ----
#pragma unroll
    for (int nt = 0; nt < 2; ++nt) {
#pragma unroll
        for (int r = 0; r < 4; ++r) {
            int n = nt * 16 + l4 * 4 + r;
            float inv = 1.0f / (Ls2[0][n] + Ls2[1][n] + 1e-9f);
#pragma unroll
            for (int ot = 0; ot < 4; ++ot) {
                int o = wv * 64 + ot * 16 + l15;
                out[(size_t)(nb + n) * O + o] = oacc[nt][ot][r] * inv;
            }
        }
    }
}

extern "C" void kernel_launch(void* const* d_in, const int* in_sizes, int n_in,
                              void* d_out, int out_size, void* d_ws, size_t ws_size,
                              hipStream_t stream) {
    const float* x   = (const float*)d_in[0];  // N x 128
    const float* cen = (const float*)d_in[1];  // 512 x 128
    const float* ls  = (const float*)d_in[2];  // 512
    const float* w   = (const float*)d_in[3];  // 256 x 512
    float* out = (float*)d_out;                // N x 256

    const int N = in_sizes[0] / D;             // 8192
    dim3 grid(N / BN), block(NT);
    hipLaunchKernelGGL(rbf_mfma, grid, block, 0, stream, x, cen, ls, w, out);
}